// Round 12
// baseline (195.040 us; speedup 1.0000x reference)
//
#include <hip/hip_runtime.h>
#include <hip/hip_bf16.h>
#include <stdint.h>

typedef unsigned short u16;
typedef __attribute__((ext_vector_type(4))) float f32x4;
typedef __attribute__((ext_vector_type(8))) __bf16 bf16x8;
typedef __attribute__((ext_vector_type(4))) __bf16 bf16x4;
typedef __attribute__((ext_vector_type(4))) unsigned int u32x4;

#define DEV __device__ __forceinline__

DEV u16 f2bf(float f){
  unsigned u = __builtin_bit_cast(unsigned, f);
  u += 0x7fffu + ((u >> 16) & 1u);
  return (u16)(u >> 16);
}

// single-instruction 2^x (args bounded; HW: exp2(-inf)=0). Pure, register-dataflow.
DEV float fexp2(float x){ float r; asm("v_exp_f32 %0, %1" : "=v"(r) : "v"(x)); return r; }

// global -> LDS direct (16B per lane; LDS dest = wave-uniform base + lane*16)
#define GL2LDS(g, l) __builtin_amdgcn_global_load_lds( \
    (const __attribute__((address_space(1))) unsigned int*)(g), \
    (__attribute__((address_space(3))) unsigned int*)(l), 16, 0, 0)

constexpr int Tt = 2048, Gg = 1024, HD = 64;
constexpr float LOG2E = 1.44269504088896340736f;

// ---------------- x -> bf16 ----------------
__global__ __launch_bounds__(256) void k_cvt_x(const float* __restrict__ x, u16* __restrict__ xb){
  long i = (long)blockIdx.x * 256 + threadIdx.x;   // 8 elems per thread
  const float4* p = (const float4*)x + 2 * i;
  float4 a = p[0], c = p[1];
  u32x4 v;
  v[0] = (unsigned)f2bf(a.x) | ((unsigned)f2bf(a.y) << 16);
  v[1] = (unsigned)f2bf(a.z) | ((unsigned)f2bf(a.w) << 16);
  v[2] = (unsigned)f2bf(c.x) | ((unsigned)f2bf(c.y) << 16);
  v[3] = (unsigned)f2bf(c.z) | ((unsigned)f2bf(c.w) << 16);
  *(u32x4*)(xb + 8 * i) = v;
}

// ---------------- weight transpose f32[k][n] -> bf16[n][k] ----------------
__global__ void k_transW(const float* __restrict__ wq, const float* __restrict__ wk,
                         const float* __restrict__ wv, const float* __restrict__ wp,
                         u16* __restrict__ wqkvT, u16* __restrict__ wpT){
  __shared__ float tile[32][33];
  int z = blockIdx.z;
  const float* w = (z == 0) ? wq : (z == 1) ? wk : (z == 2) ? wv : wp;
  u16* o = (z < 3) ? (wqkvT + (size_t)z * Gg * Gg) : wpT;
  int n0 = blockIdx.x * 32, k0 = blockIdx.y * 32;
  for (int r = threadIdx.y; r < 32; r += 8)
    tile[r][threadIdx.x] = w[(size_t)(k0 + r) * Gg + n0 + threadIdx.x];
  __syncthreads();
  for (int r = threadIdx.y; r < 32; r += 8)
    o[(size_t)(n0 + r) * Gg + k0 + threadIdx.x] = f2bf(tile[threadIdx.x][r]);
}

// ---------------- GEMM: C[M][N] = A[M][K](bf16) * Bt[N][K](bf16)^T ----------------
// 2-phase double-buffered staging (r10, proven): issue K-step k+1's global_load_lds
// BEFORE computing step k, one barrier per K-step.
template<int EPI>
__global__ __launch_bounds__(256) void k_gemm(
    const u16* __restrict__ A, const u16* __restrict__ Bt, int M, int N, int K,
    const float* __restrict__ b0, const float* __restrict__ b1, const float* __restrict__ b2,
    u16* __restrict__ q_out, u16* __restrict__ k_out, u16* __restrict__ v_out,
    float* __restrict__ out, const float* __restrict__ bp){
  __shared__ u16 lA[2][128 * 32];
  __shared__ u16 lB[2][128 * 32];
  const int tid = threadIdx.x;
  const int lane = tid & 63, w = tid >> 6;
  const int lr = lane & 15, lg = lane >> 4;
  const int wr = w >> 1, wc = w & 1;
  int bid = blockIdx.x;
  int cpx = gridDim.x >> 3;
  int sbid = (bid & 7) * cpx + (bid >> 3);
  const int nbn = N >> 7;
  const int mb = sbid / nbn, nb = sbid % nbn;
  const int m0 = mb * 128, n0 = nb * 128;

  f32x4 acc[4][4];
#pragma unroll
  for (int i = 0; i < 4; i++)
#pragma unroll
    for (int j = 0; j < 4; j++) acc[i][j] = (f32x4)0.f;

  const int lrow = lane >> 2;          // 0..15 within segment
  const int lch  = lane & 3;           // 16B chunk
  const int gswz = (lrow >> 2) & 3;
  const size_t aRow0 = (size_t)(m0 + w * 32 + lrow) * K + (lch ^ gswz) * 8;
  const size_t bRow0 = (size_t)(n0 + w * 32 + lrow) * K + (lch ^ gswz) * 8;

  // prologue: stage k0=0 into buffer 0
#pragma unroll
  for (int j = 0; j < 2; j++) {
    GL2LDS(A  + aRow0 + (size_t)j * 16 * K, &lA[0][(w * 32 + j * 16) * 32]);
    GL2LDS(Bt + bRow0 + (size_t)j * 16 * K, &lB[0][(w * 32 + j * 16) * 32]);
  }
  __syncthreads();

  int cur = 0;
  for (int k0 = 0; k0 < K; k0 += 32) {
    if (k0 + 32 < K) {
#pragma unroll
      for (int j = 0; j < 2; j++) {
        GL2LDS(A  + aRow0 + (size_t)j * 16 * K + k0 + 32, &lA[cur ^ 1][(w * 32 + j * 16) * 32]);
        GL2LDS(Bt + bRow0 + (size_t)j * 16 * K + k0 + 32, &lB[cur ^ 1][(w * 32 + j * 16) * 32]);
      }
    }
    bf16x8 af[4], bfr[4];
#pragma unroll
    for (int mi = 0; mi < 4; mi++) {
      int row = wr * 64 + mi * 16 + lr;
      int ch = lg ^ ((row >> 2) & 3);
      af[mi] = *(const bf16x8*)&lA[cur][row * 32 + ch * 8];
    }
#pragma unroll
    for (int nj = 0; nj < 4; nj++) {
      int row = wc * 64 + nj * 16 + lr;
      int ch = lg ^ ((row >> 2) & 3);
      bfr[nj] = *(const bf16x8*)&lB[cur][row * 32 + ch * 8];
    }
#pragma unroll
    for (int mi = 0; mi < 4; mi++)
#pragma unroll
      for (int nj = 0; nj < 4; nj++)
        acc[mi][nj] = __builtin_amdgcn_mfma_f32_16x16x32_bf16(af[mi], bfr[nj], acc[mi][nj], 0, 0, 0);

    __syncthreads();
    cur ^= 1;
  }

  if constexpr (EPI == 0) {
#pragma unroll
    for (int nj = 0; nj < 4; nj++) {
      int col = n0 + wc * 64 + nj * 16 + lr;     // 0..3071
      int tsel = col >> 10;
      int nn = col & 1023;
      const float* bptr = (tsel == 0) ? b0 : (tsel == 1) ? b1 : b2;
      float bias = bptr[nn];
      int h = nn >> 6, d = nn & 63;
      if (tsel == 2) {
#pragma unroll
        for (int mi = 0; mi < 4; mi++) {
          int rowb = m0 + wr * 64 + mi * 16 + lg * 4;
          int bb = rowb >> 11, t = rowb & 2047;
          int bh = bb * 16 + h;
          ushort4 pk;
          pk.x = f2bf(acc[mi][nj][0] + bias);
          pk.y = f2bf(acc[mi][nj][1] + bias);
          pk.z = f2bf(acc[mi][nj][2] + bias);
          pk.w = f2bf(acc[mi][nj][3] + bias);
          *(ushort4*)&v_out[((size_t)bh * 64 + d) * 2048 + t] = pk;
        }
      } else {
        u16* dst = (tsel == 0) ? q_out : k_out;
        const float sc = (tsel == 0) ? 0.125f * LOG2E : 1.0f;   // exp2-domain softmax
#pragma unroll
        for (int mi = 0; mi < 4; mi++) {
          int rowb = m0 + wr * 64 + mi * 16 + lg * 4;
#pragma unroll
          for (int r = 0; r < 4; r++) {
            int row = rowb + r;
            int bb = row >> 11, t = row & 2047;
            float v = (acc[mi][nj][r] + bias) * sc;
            dst[((size_t)(bb * 16 + h) * 2048 + t) * 64 + d] = f2bf(v);
          }
        }
      }
    }
  } else {
#pragma unroll
    for (int nj = 0; nj < 4; nj++) {
      int col = n0 + wc * 64 + nj * 16 + lr;
      float bias = bp[col];
#pragma unroll
      for (int mi = 0; mi < 4; mi++) {
#pragma unroll
        for (int r = 0; r < 4; r++) {
          int row = m0 + wr * 64 + mi * 16 + lg * 4 + r;
          out[(size_t)row * 1024 + col] = acc[mi][nj][r] + bias;
        }
      }
    }
  }
}

// ---------------- causal flash attention, QBLK=256, 16 waves x 16 q-rows ----------------
// Q,K bf16 [bh][T][64]; V^T bf16 [bh][64][T]; O bf16 [b][t][h*64+d].
// Q pre-scaled by 0.125*log2e -> exp2 domain.
// 16 q-rows/wave -> 8192 total waves = 100% of chip wave capacity (was 4096/50%).
// 2 blocks/CU (LDS 64KB) -> 32 waves/CU resident; during one block's barrier
// drain the other block's 16 waves issue. Per-wave body = r8 known-good code
// with the qg dimension deleted (state halves; VGPR must stay <=64 for 8/SIMD).
// Staging: waves 0-7 stage K rows [w*8,w*8+8), waves 8-15 stage V rows; one
// global_load_lds per wave per tile. LPT pairing: round 0 qb=7-g, round 1 qb=g.
__global__ __launch_bounds__(1024, 8) void k_attn(const u16* __restrict__ Qb, const u16* __restrict__ Kb,
                                                  const u16* __restrict__ Vtb, u16* __restrict__ Ob){
  __shared__ u16 lK[2][64 * 64];     // [kv][d], 128B rows, chunk^(row&7) swizzle (16 KB)
  __shared__ u16 lV[2][64 * 64];     // [d][kv], same swizzle (16 KB)
  __shared__ u16 plds[16][1024];     // per wave: [16 q][64 kv] bf16, swizzled (32 KB)
  const int tid = threadIdx.x, lane = tid & 63, w = tid >> 6;   // w in 0..15
  const int lr = lane & 15, lg = lane >> 4;
  const int slot = blockIdx.x & 255;
  const int rr = blockIdx.x >> 8;          // 0..1
  const int bh = slot & 63;
  const int g  = slot >> 6;                // 0..3
  const int qb = (rr == 0) ? 7 - g : g;    // q-block of 256 rows
  const int q0w = qb * 256 + w * 16;       // this wave's 16 q rows
  const int b = bh >> 4, h = bh & 15;
  const size_t base  = (size_t)bh * Tt * HD;   // Q,K
  const size_t vbase = (size_t)bh * HD * Tt;   // V^T
  char* pw = (char*)&plds[w][0];

  // staging: 8 rows x 8 chunks of 16B per gl2lds; waves 0-7 -> K, 8-15 -> V
  const int sl3 = lane >> 3, sc = lane & 7;
  const int r0 = (w & 7) * 8;
  const int srow = r0 + sl3;
  const int schk = (sc ^ (srow & 7)) * 8;  // pre-swizzled source chunk (elements)
  const bool isK = (w < 8);

  bf16x8 qf[2];
#pragma unroll
  for (int dh = 0; dh < 2; dh++)
    qf[dh] = *(const bf16x8*)(Qb + base + (size_t)(q0w + lr) * 64 + dh * 32 + lg * 8);

  f32x4 Oacc[4];
#pragma unroll
  for (int nf = 0; nf < 4; nf++) Oacc[nf] = (f32x4)0.f;
  float mrun = -__builtin_inff();
  float lsum = 0.f;                    // per-lane partial, reduced at end

  const int ntile = 4 * qb + 4;        // block-uniform tile count (covers rows [0, qb*256+256))

  // prologue: stage tile 0 into buffer 0
  if (isK) GL2LDS(Kb + base + (size_t)srow * 64 + schk, &lK[0][r0 * 64]);
  else     GL2LDS(Vtb + vbase + (size_t)srow * Tt + schk, &lV[0][r0 * 64]);
  __syncthreads();

  int cur = 0;
  for (int kt = 0; kt < ntile; kt++) {
    const int kv0 = kt << 6;
    // ---- issue next tile's staging (lands during compute; drained at barrier) ----
    if (kt + 1 < ntile) {
      const int nkv0 = kv0 + 64;
      if (isK) GL2LDS(Kb + base + (size_t)(nkv0 + srow) * 64 + schk, &lK[cur ^ 1][r0 * 64]);
      else     GL2LDS(Vtb + vbase + (size_t)srow * Tt + nkv0 + schk, &lV[cur ^ 1][r0 * 64]);
    }

    if (kv0 <= q0w + 15) {             // wave-uniform: tile not fully masked for this wave
      const bool full = (kv0 + 63 <= q0w);
      const u16* lKc = &lK[cur][0];
      const u16* lVc = &lV[cur][0];

      // ---- S^T = K * Q^T (row=kv 64, col=q 16) from LDS ----
      f32x4 accs[4];
#pragma unroll
      for (int kg = 0; kg < 4; kg++) {
        int row = kg * 16 + lr;
        bf16x8 kf0 = *(const bf16x8*)&lKc[row * 64 + (lg ^ (row & 7)) * 8];
        bf16x8 kf1 = *(const bf16x8*)&lKc[row * 64 + ((4 + lg) ^ (row & 7)) * 8];
        accs[kg] = __builtin_amdgcn_mfma_f32_16x16x32_bf16(kf0, qf[0], (f32x4)0.f, 0, 0, 0);
        accs[kg] = __builtin_amdgcn_mfma_f32_16x16x32_bf16(kf1, qf[1], accs[kg], 0, 0, 0);
      }

      // ---- online softmax (exp2 domain), defer-max, no cross-lane steady state ----
      float pvv[4][4];
      {
        const int q = q0w + lr;
        float tm = -__builtin_inff();
#pragma unroll
        for (int kg = 0; kg < 4; kg++)
#pragma unroll
          for (int r = 0; r < 4; r++) {
            float s = accs[kg][r];
            if (!full) { int kv = kv0 + kg * 16 + lg * 4 + r; if (kv > q) s = -__builtin_inff(); }
            pvv[kg][r] = s;
            tm = fmaxf(tm, s);
          }
        if (!__all(tm <= mrun + 8.f)) {   // T13 defer-max (P bounded by 2^8)
          float tmr = fmaxf(tm, __shfl_xor(tm, 16));
          tmr = fmaxf(tmr, __shfl_xor(tmr, 32));
          float mnew = fmaxf(mrun, tmr);
          float alpha = fexp2(mrun - mnew);
          mrun = mnew;
          lsum *= alpha;
#pragma unroll
          for (int r = 0; r < 4; r++) {
            float aO = __shfl(alpha, lg * 4 + r);
#pragma unroll
            for (int nf = 0; nf < 4; nf++) Oacc[nf][r] *= aO;
          }
        }
        const float m = mrun;
        float ps = 0.f;
#pragma unroll
        for (int kg = 0; kg < 4; kg++)
#pragma unroll
          for (int r = 0; r < 4; r++) {
            float p = fexp2(pvv[kg][r] - m);
            pvv[kg][r] = p;
            ps += p;
          }
        lsum += ps;
      }

      // ---- pack P -> per-wave LDS [16][64] (row stride 128B, chunk^rs swizzle) ----
      const int rs = lr & 7;
#pragma unroll
      for (int kg = 0; kg < 4; kg++) {
        int chunk = kg * 2 + (lg >> 1);
        int byte = lr * 128 + ((chunk ^ rs) << 4) + (lg & 1) * 8;
        bf16x4 t;
        t[0] = (__bf16)pvv[kg][0]; t[1] = (__bf16)pvv[kg][1];
        t[2] = (__bf16)pvv[kg][2]; t[3] = (__bf16)pvv[kg][3];
        *(bf16x4*)(pw + byte) = t;
      }
      // ---- PV ----
#pragma unroll
      for (int ks = 0; ks < 2; ks++) {
        bf16x8 pf = *(const bf16x8*)(pw + lr * 128 + (((ks * 4 + lg) ^ rs) << 4));
#pragma unroll
        for (int nf = 0; nf < 4; nf++) {
          int vrow = nf * 16 + lr;
          bf16x8 vf = *(const bf16x8*)&lVc[vrow * 64 + ((ks * 4 + lg) ^ (vrow & 7)) * 8];
          Oacc[nf] = __builtin_amdgcn_mfma_f32_16x16x32_bf16(pf, vf, Oacc[nf], 0, 0, 0);
        }
      }
    }

    __syncthreads();                   // drains this wave's gl2lds + buffer handoff
    cur ^= 1;
  }

  // finalize: reduce lsum across lg, O /= lsum, write [b][t][h*64+d]
  {
    float ls = lsum;
    ls += __shfl_xor(ls, 16);
    ls += __shfl_xor(ls, 32);
    float li = 1.f / ls;
#pragma unroll
    for (int r = 0; r < 4; r++) {
      float liO = __shfl(li, lg * 4 + r);
      int q = q0w + lg * 4 + r;
      size_t rowoff = ((size_t)b * Tt + q) * Gg + h * 64;
#pragma unroll
      for (int nf = 0; nf < 4; nf++)
        Ob[rowoff + nf * 16 + lr] = f2bf(Oacc[nf][r] * liO);
    }
  }
}

extern "C" void kernel_launch(void* const* d_in, const int* in_sizes, int n_in,
                              void* d_out, int out_size, void* d_ws, size_t ws_size,
                              hipStream_t stream){
  const float* x  = (const float*)d_in[0];
  const float* wq = (const float*)d_in[1];
  const float* bq = (const float*)d_in[2];
  const float* wk = (const float*)d_in[3];
  const float* bk = (const float*)d_in[4];
  const float* wv = (const float*)d_in[5];
  const float* bv = (const float*)d_in[6];
  const float* wp = (const float*)d_in[7];
  const float* bp = (const float*)d_in[8];
  float* out = (float*)d_out;
  char* ws = (char*)d_ws;

  u16* xb    = (u16*)(ws);                  // 16 MB  (8192x1024 bf16)
  u16* wqkvT = (u16*)(ws + (16l << 20));    // 6 MB   ([3072][1024] bf16)
  u16* wpT   = (u16*)(ws + (22l << 20));    // 2 MB
  u16* Qb    = (u16*)(ws + (24l << 20));    // 16 MB  ([64][2048][64] bf16)
  u16* Kb    = (u16*)(ws + (40l << 20));    // 16 MB
  u16* Vtb   = (u16*)(ws + (56l << 20));    // 16 MB  ([64][64][2048] bf16, V^T)
  u16* Ao    = (u16*)(ws + (72l << 20));    // 16 MB  ([8192][1024] bf16)

  k_cvt_x<<<dim3(4096), dim3(256), 0, stream>>>(x, xb);
  k_transW<<<dim3(32, 32, 4), dim3(32, 8), 0, stream>>>(wq, wk, wv, wp, wqkvT, wpT);
  k_gemm<0><<<dim3(64 * 24), dim3(256), 0, stream>>>(xb, wqkvT, 8192, 3072, 1024,
                                                     bq, bk, bv, Qb, Kb, Vtb, nullptr, nullptr);
  k_attn<<<dim3(512), dim3(1024), 0, stream>>>(Qb, Kb, Vtb, Ao);
  k_gemm<1><<<dim3(64 * 8), dim3(256), 0, stream>>>(Ao, wpT, 8192, 1024, 1024,
                                                    nullptr, nullptr, nullptr, nullptr, nullptr, nullptr,
                                                    out, bp);
}

// Round 13
// 180.606 us; speedup vs baseline: 1.0799x; 1.0799x over previous
//
#include <hip/hip_runtime.h>
#include <hip/hip_bf16.h>
#include <stdint.h>

typedef unsigned short u16;
typedef __attribute__((ext_vector_type(4))) float f32x4;
typedef __attribute__((ext_vector_type(8))) __bf16 bf16x8;
typedef __attribute__((ext_vector_type(4))) __bf16 bf16x4;
typedef __attribute__((ext_vector_type(4))) unsigned int u32x4;

#define DEV __device__ __forceinline__

DEV u16 f2bf(float f){
  unsigned u = __builtin_bit_cast(unsigned, f);
  u += 0x7fffu + ((u >> 16) & 1u);
  return (u16)(u >> 16);
}

// single-instruction 2^x (args bounded; HW: exp2(-inf)=0). Pure, register-dataflow.
DEV float fexp2(float x){ float r; asm("v_exp_f32 %0, %1" : "=v"(r) : "v"(x)); return r; }

// global -> LDS direct (16B per lane; LDS dest = wave-uniform base + lane*16)
#define GL2LDS(g, l) __builtin_amdgcn_global_load_lds( \
    (const __attribute__((address_space(1))) unsigned int*)(g), \
    (__attribute__((address_space(3))) unsigned int*)(l), 16, 0, 0)

constexpr int Tt = 2048, Gg = 1024, HD = 64;
constexpr float LOG2E = 1.44269504088896340736f;

// ---------------- fused pre-pass: x->bf16 (blocks 0..4095) + weight transpose (4096..8191) ----------------
__global__ __launch_bounds__(256) void k_prep(const float* __restrict__ x, u16* __restrict__ xb,
                                              const float* __restrict__ wq, const float* __restrict__ wk,
                                              const float* __restrict__ wv, const float* __restrict__ wp,
                                              u16* __restrict__ wqkvT, u16* __restrict__ wpT){
  __shared__ float tile[32][33];
  const int tid = threadIdx.x;
  if (blockIdx.x < 4096) {
    // x -> bf16, 8 elems per thread
    long i = (long)blockIdx.x * 256 + tid;
    const float4* p = (const float4*)x + 2 * i;
    float4 a = p[0], c = p[1];
    u32x4 v;
    v[0] = (unsigned)f2bf(a.x) | ((unsigned)f2bf(a.y) << 16);
    v[1] = (unsigned)f2bf(a.z) | ((unsigned)f2bf(a.w) << 16);
    v[2] = (unsigned)f2bf(c.x) | ((unsigned)f2bf(c.y) << 16);
    v[3] = (unsigned)f2bf(c.z) | ((unsigned)f2bf(c.w) << 16);
    *(u32x4*)(xb + 8 * i) = v;
  } else {
    // weight transpose f32[k][n] -> bf16[n][k]
    const int r = blockIdx.x - 4096;         // 0..4095
    const int z = r >> 10;                   // 0..3
    const int rem = r & 1023;
    const int n0 = (rem & 31) * 32, k0 = (rem >> 5) * 32;
    const int tx = tid & 31, ty = tid >> 5;  // (32,8)
    const float* w = (z == 0) ? wq : (z == 1) ? wk : (z == 2) ? wv : wp;
    u16* o = (z < 3) ? (wqkvT + (size_t)z * Gg * Gg) : wpT;
    for (int rr = ty; rr < 32; rr += 8)
      tile[rr][tx] = w[(size_t)(k0 + rr) * Gg + n0 + tx];
    __syncthreads();
    for (int rr = ty; rr < 32; rr += 8)
      o[(size_t)(n0 + rr) * Gg + k0 + tx] = f2bf(tile[tx][rr]);
  }
}

// ---------------- GEMM: C[M][N] = A[M][K](bf16) * Bt[N][K](bf16)^T ----------------
// 2-phase double-buffered staging (r10, proven): issue K-step k+1's global_load_lds
// BEFORE computing step k, one barrier per K-step.
template<int EPI>
__global__ __launch_bounds__(256) void k_gemm(
    const u16* __restrict__ A, const u16* __restrict__ Bt, int M, int N, int K,
    const float* __restrict__ b0, const float* __restrict__ b1, const float* __restrict__ b2,
    u16* __restrict__ q_out, u16* __restrict__ k_out, u16* __restrict__ v_out,
    float* __restrict__ out, const float* __restrict__ bp){
  __shared__ u16 lA[2][128 * 32];
  __shared__ u16 lB[2][128 * 32];
  const int tid = threadIdx.x;
  const int lane = tid & 63, w = tid >> 6;
  const int lr = lane & 15, lg = lane >> 4;
  const int wr = w >> 1, wc = w & 1;
  int bid = blockIdx.x;
  int cpx = gridDim.x >> 3;
  int sbid = (bid & 7) * cpx + (bid >> 3);
  const int nbn = N >> 7;
  const int mb = sbid / nbn, nb = sbid % nbn;
  const int m0 = mb * 128, n0 = nb * 128;

  f32x4 acc[4][4];
#pragma unroll
  for (int i = 0; i < 4; i++)
#pragma unroll
    for (int j = 0; j < 4; j++) acc[i][j] = (f32x4)0.f;

  const int lrow = lane >> 2;          // 0..15 within segment
  const int lch  = lane & 3;           // 16B chunk
  const int gswz = (lrow >> 2) & 3;
  const size_t aRow0 = (size_t)(m0 + w * 32 + lrow) * K + (lch ^ gswz) * 8;
  const size_t bRow0 = (size_t)(n0 + w * 32 + lrow) * K + (lch ^ gswz) * 8;

  // prologue: stage k0=0 into buffer 0
#pragma unroll
  for (int j = 0; j < 2; j++) {
    GL2LDS(A  + aRow0 + (size_t)j * 16 * K, &lA[0][(w * 32 + j * 16) * 32]);
    GL2LDS(Bt + bRow0 + (size_t)j * 16 * K, &lB[0][(w * 32 + j * 16) * 32]);
  }
  __syncthreads();

  int cur = 0;
  for (int k0 = 0; k0 < K; k0 += 32) {
    if (k0 + 32 < K) {
#pragma unroll
      for (int j = 0; j < 2; j++) {
        GL2LDS(A  + aRow0 + (size_t)j * 16 * K + k0 + 32, &lA[cur ^ 1][(w * 32 + j * 16) * 32]);
        GL2LDS(Bt + bRow0 + (size_t)j * 16 * K + k0 + 32, &lB[cur ^ 1][(w * 32 + j * 16) * 32]);
      }
    }
    bf16x8 af[4], bfr[4];
#pragma unroll
    for (int mi = 0; mi < 4; mi++) {
      int row = wr * 64 + mi * 16 + lr;
      int ch = lg ^ ((row >> 2) & 3);
      af[mi] = *(const bf16x8*)&lA[cur][row * 32 + ch * 8];
    }
#pragma unroll
    for (int nj = 0; nj < 4; nj++) {
      int row = wc * 64 + nj * 16 + lr;
      int ch = lg ^ ((row >> 2) & 3);
      bfr[nj] = *(const bf16x8*)&lB[cur][row * 32 + ch * 8];
    }
#pragma unroll
    for (int mi = 0; mi < 4; mi++)
#pragma unroll
      for (int nj = 0; nj < 4; nj++)
        acc[mi][nj] = __builtin_amdgcn_mfma_f32_16x16x32_bf16(af[mi], bfr[nj], acc[mi][nj], 0, 0, 0);

    __syncthreads();
    cur ^= 1;
  }

  if constexpr (EPI == 0) {
#pragma unroll
    for (int nj = 0; nj < 4; nj++) {
      int col = n0 + wc * 64 + nj * 16 + lr;     // 0..3071
      int tsel = col >> 10;
      int nn = col & 1023;
      const float* bptr = (tsel == 0) ? b0 : (tsel == 1) ? b1 : b2;
      float bias = bptr[nn];
      int h = nn >> 6, d = nn & 63;
      if (tsel == 2) {
#pragma unroll
        for (int mi = 0; mi < 4; mi++) {
          int rowb = m0 + wr * 64 + mi * 16 + lg * 4;
          int bb = rowb >> 11, t = rowb & 2047;
          int bh = bb * 16 + h;
          ushort4 pk;
          pk.x = f2bf(acc[mi][nj][0] + bias);
          pk.y = f2bf(acc[mi][nj][1] + bias);
          pk.z = f2bf(acc[mi][nj][2] + bias);
          pk.w = f2bf(acc[mi][nj][3] + bias);
          *(ushort4*)&v_out[((size_t)bh * 64 + d) * 2048 + t] = pk;
        }
      } else {
        u16* dst = (tsel == 0) ? q_out : k_out;
        const float sc = (tsel == 0) ? 0.125f * LOG2E : 1.0f;   // exp2-domain softmax
#pragma unroll
        for (int mi = 0; mi < 4; mi++) {
          int rowb = m0 + wr * 64 + mi * 16 + lg * 4;
#pragma unroll
          for (int r = 0; r < 4; r++) {
            int row = rowb + r;
            int bb = row >> 11, t = row & 2047;
            float v = (acc[mi][nj][r] + bias) * sc;
            dst[((size_t)(bb * 16 + h) * 2048 + t) * 64 + d] = f2bf(v);
          }
        }
      }
    }
  } else {
#pragma unroll
    for (int nj = 0; nj < 4; nj++) {
      int col = n0 + wc * 64 + nj * 16 + lr;
      float bias = bp[col];
#pragma unroll
      for (int mi = 0; mi < 4; mi++) {
#pragma unroll
        for (int r = 0; r < 4; r++) {
          int row = m0 + wr * 64 + mi * 16 + lg * 4 + r;
          out[(size_t)row * 1024 + col] = acc[mi][nj][r] + bias;
        }
      }
    }
  }
}

// ---------------- causal flash attention, QBLK=256 (8 waves x 32 q-rows), KVBLK=64 ----------------
// r11 exact body (best measured: 81.0 us). Q,K bf16 [bh][T][64]; V^T bf16 [bh][64][T];
// O bf16 [b][t][h*64+d]. Q pre-scaled by 0.125*log2e -> exp2 domain.
// LPT pairing: round 0 qb=7-g (heavy), round 1 qb=g -> uniform 36 tile-units/CU.
__global__ __launch_bounds__(512, 4) void k_attn(const u16* __restrict__ Qb, const u16* __restrict__ Kb,
                                                 const u16* __restrict__ Vtb, u16* __restrict__ Ob){
  __shared__ u16 lK[2][64 * 64];     // [kv][d], 128B rows, chunk^(row&7) swizzle (16 KB)
  __shared__ u16 lV[2][64 * 64];     // [d][kv], same swizzle (16 KB)
  __shared__ u16 plds[8][1024];      // per wave: one qg [16 q][64 kv], swizzled (16 KB)
  const int tid = threadIdx.x, lane = tid & 63, w = tid >> 6;   // w in 0..7
  const int lr = lane & 15, lg = lane >> 4;
  const int slot = blockIdx.x & 255;
  const int rr = blockIdx.x >> 8;          // 0..1
  const int bh = slot & 63;
  const int g  = slot >> 6;                // 0..3
  const int qb = (rr == 0) ? 7 - g : g;    // q-block of 256 rows
  const int q0w = qb * 256 + w * 32;       // this wave's 32 q rows
  const int b = bh >> 4, h = bh & 15;
  const size_t base  = (size_t)bh * Tt * HD;   // Q,K
  const size_t vbase = (size_t)bh * HD * Tt;   // V^T
  char* pw = (char*)&plds[w][0];

  // staging lane geometry: 8 rows x 8 chunks of 16B per instruction; wave stages rows [w*8, w*8+8)
  const int sl3 = lane >> 3, sc = lane & 7;
  const int r0 = w * 8;
  const int srow = r0 + sl3;
  const int schk = (sc ^ (srow & 7)) * 8;  // pre-swizzled source chunk (elements)

  bf16x8 qf[2][2];
#pragma unroll
  for (int qg = 0; qg < 2; qg++)
#pragma unroll
    for (int dh = 0; dh < 2; dh++)
      qf[qg][dh] = *(const bf16x8*)(Qb + base + (size_t)(q0w + qg * 16 + lr) * 64 + dh * 32 + lg * 8);

  f32x4 Oacc[2][4];
#pragma unroll
  for (int qg = 0; qg < 2; qg++)
#pragma unroll
    for (int nf = 0; nf < 4; nf++) Oacc[qg][nf] = (f32x4)0.f;
  float mrun[2] = {-__builtin_inff(), -__builtin_inff()};
  float lsum[2] = {0.f, 0.f};          // per-lane partials, reduced at end

  const int ntile = 4 * qb + 4;        // block-uniform tile count (covers rows [0, qb*256+256))

  // prologue: stage tile 0 into buffer 0 (each wave: 1 K-row-slab + 1 V-row-slab)
  GL2LDS(Kb + base + (size_t)srow * 64 + schk, &lK[0][r0 * 64]);
  GL2LDS(Vtb + vbase + (size_t)srow * Tt + schk, &lV[0][r0 * 64]);
  __syncthreads();

  int cur = 0;
  for (int kt = 0; kt < ntile; kt++) {
    const int kv0 = kt << 6;
    // ---- issue next tile's staging (lands during compute; drained at barrier) ----
    if (kt + 1 < ntile) {
      const int nkv0 = kv0 + 64;
      GL2LDS(Kb + base + (size_t)(nkv0 + srow) * 64 + schk, &lK[cur ^ 1][r0 * 64]);
      GL2LDS(Vtb + vbase + (size_t)srow * Tt + nkv0 + schk, &lV[cur ^ 1][r0 * 64]);
    }

    if (kv0 <= q0w + 31) {             // wave-uniform: tile not fully masked for this wave
      const bool full = (kv0 + 63 <= q0w);
      const u16* lKc = &lK[cur][0];
      const u16* lVc = &lV[cur][0];

      // ---- S^T = K * Q^T (row=kv 64, col=q 32) from LDS ----
      f32x4 accs[4][2];
#pragma unroll
      for (int kg = 0; kg < 4; kg++) {
        int row = kg * 16 + lr;
        bf16x8 kf0 = *(const bf16x8*)&lKc[row * 64 + (lg ^ (row & 7)) * 8];
        bf16x8 kf1 = *(const bf16x8*)&lKc[row * 64 + ((4 + lg) ^ (row & 7)) * 8];
#pragma unroll
        for (int qg = 0; qg < 2; qg++) {
          accs[kg][qg] = __builtin_amdgcn_mfma_f32_16x16x32_bf16(kf0, qf[qg][0], (f32x4)0.f, 0, 0, 0);
          accs[kg][qg] = __builtin_amdgcn_mfma_f32_16x16x32_bf16(kf1, qf[qg][1], accs[kg][qg], 0, 0, 0);
        }
      }

      // ---- online softmax (exp2 domain), defer-max, no cross-lane steady state ----
      float pvv[2][4][4];
#pragma unroll
      for (int qg = 0; qg < 2; qg++) {
        const int q = q0w + qg * 16 + lr;
        float tm = -__builtin_inff();
#pragma unroll
        for (int kg = 0; kg < 4; kg++)
#pragma unroll
          for (int r = 0; r < 4; r++) {
            float s = accs[kg][qg][r];
            if (!full) { int kv = kv0 + kg * 16 + lg * 4 + r; if (kv > q) s = -__builtin_inff(); }
            pvv[qg][kg][r] = s;
            tm = fmaxf(tm, s);
          }
        if (!__all(tm <= mrun[qg] + 8.f)) {   // T13 defer-max (P bounded by 2^8)
          float tmr = fmaxf(tm, __shfl_xor(tm, 16));
          tmr = fmaxf(tmr, __shfl_xor(tmr, 32));
          float mnew = fmaxf(mrun[qg], tmr);
          float alpha = fexp2(mrun[qg] - mnew);
          mrun[qg] = mnew;
          lsum[qg] *= alpha;
#pragma unroll
          for (int r = 0; r < 4; r++) {
            float aO = __shfl(alpha, lg * 4 + r);
#pragma unroll
            for (int nf = 0; nf < 4; nf++) Oacc[qg][nf][r] *= aO;
          }
        }
        const float m = mrun[qg];
        float ps = 0.f;
#pragma unroll
        for (int kg = 0; kg < 4; kg++)
#pragma unroll
          for (int r = 0; r < 4; r++) {
            float p = fexp2(pvv[qg][kg][r] - m);
            pvv[qg][kg][r] = p;
            ps += p;
          }
        lsum[qg] += ps;
      }

      // ---- PV per qg; V fragments loaded once (lazily at qg==0), reused for qg=1 ----
      bf16x8 vfr[2][4];
      const int rs = lr & 7;
#pragma unroll
      for (int qg = 0; qg < 2; qg++) {
        // pack P -> per-wave LDS [16][64] (row stride 128B, chunk^rs swizzle)
#pragma unroll
        for (int kg = 0; kg < 4; kg++) {
          int chunk = kg * 2 + (lg >> 1);
          int byte = lr * 128 + ((chunk ^ rs) << 4) + (lg & 1) * 8;
          bf16x4 t;
          t[0] = (__bf16)pvv[qg][kg][0]; t[1] = (__bf16)pvv[qg][kg][1];
          t[2] = (__bf16)pvv[qg][kg][2]; t[3] = (__bf16)pvv[qg][kg][3];
          *(bf16x4*)(pw + byte) = t;
        }
#pragma unroll
        for (int ks = 0; ks < 2; ks++) {
          bf16x8 pf = *(const bf16x8*)(pw + lr * 128 + (((ks * 4 + lg) ^ rs) << 4));
#pragma unroll
          for (int nf = 0; nf < 4; nf++) {
            if (qg == 0) {
              int vrow = nf * 16 + lr;
              vfr[ks][nf] = *(const bf16x8*)&lVc[vrow * 64 + ((ks * 4 + lg) ^ (vrow & 7)) * 8];
            }
            Oacc[qg][nf] = __builtin_amdgcn_mfma_f32_16x16x32_bf16(pf, vfr[ks][nf], Oacc[qg][nf], 0, 0, 0);
          }
        }
      }
    }

    __syncthreads();                   // drains this wave's gl2lds + buffer handoff
    cur ^= 1;
  }

  // finalize: reduce lsum across lg, O /= lsum, write [b][t][h*64+d]
#pragma unroll
  for (int qg = 0; qg < 2; qg++) {
    float ls = lsum[qg];
    ls += __shfl_xor(ls, 16);
    ls += __shfl_xor(ls, 32);
    float li = 1.f / ls;
#pragma unroll
    for (int r = 0; r < 4; r++) {
      float liO = __shfl(li, lg * 4 + r);
      int q = q0w + qg * 16 + lg * 4 + r;
      size_t rowoff = ((size_t)b * Tt + q) * Gg + h * 64;
#pragma unroll
      for (int nf = 0; nf < 4; nf++)
        Ob[rowoff + nf * 16 + lr] = f2bf(Oacc[qg][nf][r] * liO);
    }
  }
}

extern "C" void kernel_launch(void* const* d_in, const int* in_sizes, int n_in,
                              void* d_out, int out_size, void* d_ws, size_t ws_size,
                              hipStream_t stream){
  const float* x  = (const float*)d_in[0];
  const float* wq = (const float*)d_in[1];
  const float* bq = (const float*)d_in[2];
  const float* wk = (const float*)d_in[3];
  const float* bk = (const float*)d_in[4];
  const float* wv = (const float*)d_in[5];
  const float* bv = (const float*)d_in[6];
  const float* wp = (const float*)d_in[7];
  const float* bp = (const float*)d_in[8];
  float* out = (float*)d_out;
  char* ws = (char*)d_ws;

  u16* xb    = (u16*)(ws);                  // 16 MB  (8192x1024 bf16)
  u16* wqkvT = (u16*)(ws + (16l << 20));    // 6 MB   ([3072][1024] bf16)
  u16* wpT   = (u16*)(ws + (22l << 20));    // 2 MB
  u16* Qb    = (u16*)(ws + (24l << 20));    // 16 MB  ([64][2048][64] bf16)
  u16* Kb    = (u16*)(ws + (40l << 20));    // 16 MB
  u16* Vtb   = (u16*)(ws + (56l << 20));    // 16 MB  ([64][64][2048] bf16, V^T)
  u16* Ao    = (u16*)(ws + (72l << 20));    // 16 MB  ([8192][1024] bf16)

  k_prep<<<dim3(8192), dim3(256), 0, stream>>>(x, xb, wq, wk, wv, wp, wqkvT, wpT);
  k_gemm<0><<<dim3(64 * 24), dim3(256), 0, stream>>>(xb, wqkvT, 8192, 3072, 1024,
                                                     bq, bk, bv, Qb, Kb, Vtb, nullptr, nullptr);
  k_attn<<<dim3(512), dim3(512), 0, stream>>>(Qb, Kb, Vtb, Ao);
  k_gemm<1><<<dim3(64 * 8), dim3(256), 0, stream>>>(Ao, wpT, 8192, 1024, 1024,
                                                    nullptr, nullptr, nullptr, nullptr, nullptr, nullptr,
                                                    out, bp);
}